// Round 1
// baseline (5868.124 us; speedup 1.0000x reference)
//
#include <hip/hip_runtime.h>
#include <math.h>

#define Bq 4
#define Mq 500
#define Nq 500
#define Cq 91

// ---------------------------------------------------------------------------
// Phase 1: cost[b,i,j] = 0.5*||center2_i - center1_j||_2
//                      + 0.5*max_c |sigmoid(l2[i,c]) - sigmoid(l1[j,c])|
// ---------------------------------------------------------------------------
__device__ __forceinline__ float sigmoidf_(float x) {
    return 1.0f / (1.0f + expf(-x));
}

__global__ __launch_bounds__(256) void cost_kernel(
    const float* __restrict__ p1_boxes, const float* __restrict__ p1_logits,
    const float* __restrict__ p2_boxes, const float* __restrict__ p2_logits,
    float* __restrict__ cost)
{
    __shared__ float s2t[16][Cq + 1];   // stride 92 -> 2-way bank alias (free)
    __shared__ float s1t[16][Cq + 1];
    __shared__ float b2x[16], b2y[16], b1x[16], b1y[16];
    const int b  = blockIdx.z;
    const int i0 = blockIdx.y * 16;
    const int j0 = blockIdx.x * 16;
    const int tid = threadIdx.x;

    for (int t = tid; t < 16 * Cq; t += 256) {
        const int r = t / Cq, c = t - r * Cq;
        const int i = min(i0 + r, Mq - 1);
        const int j = min(j0 + r, Nq - 1);
        s2t[r][c] = sigmoidf_(p2_logits[((size_t)b * Mq + i) * Cq + c]);
        s1t[r][c] = sigmoidf_(p1_logits[((size_t)b * Nq + j) * Cq + c]);
    }
    if (tid < 16) {
        const int i = min(i0 + tid, Mq - 1);
        const int j = min(j0 + tid, Nq - 1);
        b2x[tid] = p2_boxes[((size_t)b * Mq + i) * 4 + 0];
        b2y[tid] = p2_boxes[((size_t)b * Mq + i) * 4 + 1];
        b1x[tid] = p1_boxes[((size_t)b * Nq + j) * 4 + 0];
        b1y[tid] = p1_boxes[((size_t)b * Nq + j) * 4 + 1];
    }
    __syncthreads();

    const int ty = tid >> 4, tx = tid & 15;
    const int i = i0 + ty, j = j0 + tx;
    if (i < Mq && j < Nq) {
        float mx = 0.0f;
        #pragma unroll 7
        for (int c = 0; c < Cq; ++c)
            mx = fmaxf(mx, fabsf(s2t[ty][c] - s1t[tx][c]));
        const float dx = b2x[ty] - b1x[tx];
        const float dy = b2y[ty] - b1y[tx];
        const float cd = sqrtf(dx * dx + dy * dy);
        cost[((size_t)b * Mq + i) * Nq + j] = 0.5f * cd + 0.5f * mx;
    }
}

// ---------------------------------------------------------------------------
// Phase 1.5: column reduction. v0[b][j] = min_i cost[b][i][j], amin = argmin.
// ---------------------------------------------------------------------------
__global__ __launch_bounds__(256) void colred_kernel(
    const float* __restrict__ cost, float* __restrict__ v0, int* __restrict__ amin)
{
    const int j = blockIdx.x * 256 + threadIdx.x;
    const int b = blockIdx.y;
    if (j >= Nq) return;
    const float* __restrict__ cb = cost + (size_t)b * Mq * Nq;
    float best = INFINITY;
    int bi = 0;
    #pragma unroll 4
    for (int i = 0; i < Mq; ++i) {
        const float c = cb[(size_t)i * Nq + j];
        if (c < best) { best = c; bi = i; }
    }
    v0[b * Nq + j] = best;
    amin[b * Nq + j] = bi;
}

// ---------------------------------------------------------------------------
// Fused-DPP wave64 min reductions (VALU-only; v_min_*_dpp single instr).
// row_shr 1/2/4/8 + row_bcast15/31 into lane 63; readlane broadcasts.
// Proven correct in R3 (absmax 0.0).
// ---------------------------------------------------------------------------
template<int CTRL>
__device__ __forceinline__ float dppmin_f32_(float x) {
    const int moved = __builtin_amdgcn_update_dpp(
        0x7F800000, __float_as_int(x), CTRL, 0xF, 0xF, false);
    return fminf(x, __int_as_float(moved));
}
__device__ __forceinline__ float wave_min_f32_(float x) {
    x = dppmin_f32_<0x111>(x);
    x = dppmin_f32_<0x112>(x);
    x = dppmin_f32_<0x114>(x);
    x = dppmin_f32_<0x118>(x);
    x = dppmin_f32_<0x142>(x);
    x = dppmin_f32_<0x143>(x);
    return __int_as_float(__builtin_amdgcn_readlane(__float_as_int(x), 63));
}
template<int CTRL>
__device__ __forceinline__ unsigned dppmin_u32_(unsigned x) {
    const unsigned moved = (unsigned)__builtin_amdgcn_update_dpp(
        (int)0xFFFFFFFFu, (int)x, CTRL, 0xF, 0xF, false);
    return x < moved ? x : moved;
}
__device__ __forceinline__ unsigned wave_min_u32_(unsigned x) {
    x = dppmin_u32_<0x111>(x);
    x = dppmin_u32_<0x112>(x);
    x = dppmin_u32_<0x114>(x);
    x = dppmin_u32_<0x118>(x);
    x = dppmin_u32_<0x142>(x);
    x = dppmin_u32_<0x143>(x);
    return (unsigned)__builtin_amdgcn_readlane((int)x, 63);
}

__device__ __forceinline__ float min8_(const float* d) {
    return fminf(fminf(fminf(d[0], d[1]), fminf(d[2], d[3])),
                 fminf(fminf(d[4], d[5]), fminf(d[6], d[7])));
}
// exact-equality payload select (g is bit-exact one of the d's); lowest j wins
__device__ __forceinline__ int argsel_(const float* d, float g, int lane) {
    unsigned sel = 0xFFFFFFFFu;
    #pragma unroll
    for (int k = 7; k >= 0; --k)
        if (d[k] == g) sel = (unsigned)(lane + (k << 6));
    return (int)wave_min_u32_(sel);
}

// ---------------------------------------------------------------------------
// Phase 2: exact LAP. One block = one batch, ONE wave. Lane L owns cols
// {L, L+64, ...}. New this round: Jonker-Volgenant initialization
// (reduction transfer + 2 rounds of augmenting row reduction) inserted
// between the greedy tight-edge match and the successive-shortest-path
// phase. Every step maintains dual feasibility (c-u-v >= 0) and tightness
// of assigned edges, so the SSP phase (unchanged, proven) still computes
// the exact (unique) optimum -- it just starts with far fewer free rows
// and much tighter duals.
// ---------------------------------------------------------------------------
__global__ __launch_bounds__(64) void lsa_kernel(
    const float* __restrict__ cost, const float* __restrict__ v0,
    const int* __restrict__ amin, int* __restrict__ mapping)
{
    constexpr int n = Nq;  // 500
    __shared__ float u_lds[512];
    __shared__ float shortest_lds[512];
    __shared__ int   path_lds[512];
    __shared__ int   row4col_lds[512];
    __shared__ int   col4row_lds[512];
    __shared__ int   fa_lds[512];      // ARR free-row worklist (current round)
    __shared__ int   fb_lds[512];      // ARR free-row worklist (next round)

    const int lane = threadIdx.x;
    const int b = blockIdx.x;
    const float* __restrict__ cb = cost + (size_t)b * n * n;

    const unsigned init_mask = (lane < (n & 63)) ? 0xFFu : 0x7Fu;  // k=7 valid iff lane<52

    float v_r[8], vwork_r[8], short_r[8], shortfin_r[8], t_r[8];
    int path_r[8];
    unsigned pay_r[8];   // (j<<10) | (row4col[j]+1)

    // --- init: duals from column reduction, greedy matching on tight edges ---
    #pragma unroll
    for (int k = 0; k < 8; ++k) {
        const int j = lane + (k << 6);
        const bool valid = (init_mask >> k) & 1;
        v_r[k] = valid ? v0[b * n + j] : 0.0f;
        vwork_r[k] = valid ? v_r[k] : -INFINITY;
        short_r[k] = INFINITY;
        shortfin_r[k] = INFINITY;
        path_r[k] = -1;
    }
    for (int t = lane; t < n; t += 64)
        path_lds[t] = amin[b * n + t];            // stash argmins for lane0
    for (int t = lane; t < 512; t += 64) {
        u_lds[t] = 0.0f; row4col_lds[t] = -1; col4row_lds[t] = -1;
    }
    __syncthreads();
    if (lane == 0) {
        for (int j = 0; j < n; ++j) {
            const int i0 = path_lds[j];
            if (col4row_lds[i0] < 0) { col4row_lds[i0] = j; row4col_lds[j] = i0; }
        }
    }
    __syncthreads();

    // =====================================================================
    // Phase A: reduction transfer (JV). For each assigned row i with col j1:
    //   mu = min_{j != j1} (c[i][j] - v[j]);  v[j1] -= mu;  u[i] = mu.
    // Keeps (i,j1) tight (c - v_new = mu = u[i]) and all other cols >= mu.
    // Assigned cols are distinct, so no later step un-tightens an edge.
    // =====================================================================
    for (int i2 = 0; i2 < n; ++i2) {
        const int j1 = col4row_lds[i2];            // uniform broadcast read
        if (j1 < 0) continue;
        const float* __restrict__ crow = cb + (size_t)i2 * n;
        float d[8];
        #pragma unroll
        for (int k = 0; k < 8; ++k) {
            const int j = lane + (k << 6);
            const float cv = crow[j < n ? j : 0];
            d[k] = ((init_mask >> k) & 1) ? cv - v_r[k] : INFINITY;
        }
        const int owner = j1 & 63, kwin = j1 >> 6;
        #pragma unroll
        for (int k = 0; k < 8; ++k)
            if (k == kwin && lane == owner) d[k] = INFINITY;   // exclude j1
        const float mu = wave_min_f32_(min8_(d));
        #pragma unroll
        for (int k = 0; k < 8; ++k)
            if (k == kwin && lane == owner) v_r[k] -= mu;
        if (lane == 0) u_lds[i2] = mu;
    }
    __syncthreads();

    // =====================================================================
    // Phase B: augmenting row reduction (JV), 2 rounds. Each free row i:
    // find m1@j1 (min reduced cost) and m2@j2 (second min).
    //   m1 < m2 : v[j1] -= (m2-m1); assign i->j1 (steal if occupied and
    //             immediately reprocess the displaced row -- strict v
    //             decrease guarantees progress);
    //   m1 == m2: if j1 occupied try j2; assign; displaced row deferred
    //             to the next round.
    // u[i] = m2 in all cases => assigned edge tight, all cols >= u[i].
    // Guard (6n scans) bounds float-tie pathologies; a guard trip just
    // leaves more rows to the exact SSP phase.
    // =====================================================================
    {
        int cnt = 0;
        for (int i2 = 0; i2 < n; ++i2) {
            if (col4row_lds[i2] < 0) { if (lane == 0) fa_lds[cnt] = i2; ++cnt; }
        }
        __syncthreads();

        int guard = 6 * n;
        for (int round = 0; round < 2 && cnt > 0; ++round) {
            int ncnt = 0;
            for (int kf = 0; kf < cnt && guard > 0; ++kf) {
                int i = fa_lds[kf];                // uniform broadcast read
                bool again = true;
                while (again && guard-- > 0) {
                    again = false;
                    const float* __restrict__ crow = cb + (size_t)i * n;
                    float d[8];
                    #pragma unroll
                    for (int k = 0; k < 8; ++k) {
                        const int j = lane + (k << 6);
                        const float cv = crow[j < n ? j : 0];
                        d[k] = ((init_mask >> k) & 1) ? cv - v_r[k] : INFINITY;
                    }
                    const float m1 = wave_min_f32_(min8_(d));
                    int j1 = argsel_(d, m1, lane);
                    {   // exclude j1, find second min
                        const int owner = j1 & 63, kwin = j1 >> 6;
                        #pragma unroll
                        for (int k = 0; k < 8; ++k)
                            if (k == kwin && lane == owner) d[k] = INFINITY;
                    }
                    const float m2 = wave_min_f32_(min8_(d));
                    const int j2 = argsel_(d, m2, lane);

                    int i0 = row4col_lds[j1];      // uniform (read BEFORE write)
                    if (m1 < m2) {
                        const int owner = j1 & 63, kwin = j1 >> 6;
                        #pragma unroll
                        for (int k = 0; k < 8; ++k)
                            if (k == kwin && lane == owner) v_r[k] -= (m2 - m1);
                    } else if (i0 >= 0) {
                        j1 = j2;
                        i0 = row4col_lds[j1];
                    }
                    if (lane == 0) {
                        row4col_lds[j1] = i;
                        col4row_lds[i]  = j1;
                        u_lds[i]        = m2;
                    }
                    if (i0 >= 0) {
                        if (lane == 0) col4row_lds[i0] = -1;
                        if (m1 < m2) { i = i0; again = true; }
                        else         { if (lane == 0) fb_lds[ncnt] = i0; ++ncnt; }
                    }
                    __syncthreads();   // publish LDS state before next scan
                }
            }
            cnt = ncnt;
            for (int t = lane; t < ncnt; t += 64) fa_lds[t] = fb_lds[t];
            __syncthreads();
            if (guard <= 0) break;
        }
    }

    // refresh register duals/payloads to the post-ARR state
    #pragma unroll
    for (int k = 0; k < 8; ++k) {
        const int j = lane + (k << 6);
        const bool valid = (init_mask >> k) & 1;
        vwork_r[k] = valid ? v_r[k] : -INFINITY;
        pay_r[k] = valid ? (((unsigned)j << 10) | (unsigned)(row4col_lds[j] + 1))
                         : 0xFFFFFFFFu;
    }
    for (int t = lane; t < n; t += 64)
        path_lds[t] = -1;
    unsigned sr_mask = 0;
    __syncthreads();

    // --- successive shortest paths over remaining free rows (unchanged) ---
    for (int cur_row = 0; cur_row < n; ++cur_row) {
        if (col4row_lds[cur_row] >= 0) continue;   // wave-uniform

        int sink_j = -1;
        int i = cur_row;
        float min_val = 0.0f;
        float a = -u_lds[cur_row];                  // a = min_val - u[i]
        const float* __restrict__ crow = cb + (size_t)i * n;

        for (int pops = 0; pops < n; ++pops) {
            if ((i & 63) == lane) sr_mask |= 1u << (i >> 6);

            // 8 coalesced row loads (strided); t_r fills the load shadow
            float cv[8];
            #pragma unroll
            for (int k = 0; k < 8; ++k) {
                const int j = lane + (k << 6);
                cv[k] = crow[j < n ? j : 0];
            }
            #pragma unroll
            for (int k = 0; k < 8; ++k) t_r[k] = a - vwork_r[k];

            // relax: 4 ops/col
            #pragma unroll
            for (int k = 0; k < 8; ++k) {
                const float r = cv[k] + t_r[k];
                if (r < short_r[k]) { short_r[k] = r; path_r[k] = i; }
            }

            // local min (bit-exact), wave min, payload select, payload tree
            const float lmin = min8_(short_r);
            const float gmin = wave_min_f32_(lmin);

            unsigned sel = 0xFFFFFFFFu;
            #pragma unroll
            for (int k = 7; k >= 0; --k)          // k ascending priority -> lowest j
                if (short_r[k] == gmin) sel = pay_r[k];
            const unsigned win = wave_min_u32_(sel);

            min_val = gmin;
            const unsigned jst = win >> 10;
            const unsigned rc1 = win & 0x3FFu;

            // pop bookkeeping: poison winner col on its owner lane (uniform k)
            const int owner = (int)(jst & 63u);
            const int kwin = (int)(jst >> 6);
            #pragma unroll
            for (int k = 0; k < 8; ++k) {
                if (k == kwin && lane == owner) {
                    shortfin_r[k] = short_r[k];
                    short_r[k] = INFINITY;
                    vwork_r[k] = -INFINITY;
                }
            }

            if (rc1 == 0u) { sink_j = (int)jst; break; }
            i = (int)rc1 - 1;
            crow = cb + (size_t)i * n;
            a = min_val - u_lds[i];   // broadcast LDS read, hides under row loads
        }

        if (sink_j >= 0) {
            // publish final labels/path (only scanned cols are ever read)
            #pragma unroll
            for (int k = 0; k < 8; ++k) {
                const int j = lane + (k << 6);
                if (j < n) {
                    shortest_lds[j] = shortfin_r[k];
                    path_lds[j] = path_r[k];
                }
            }
            __syncthreads();

            // u-update for SR rows (col4row read BEFORE augmentation);
            // v-update for scanned cols (marker: vwork == -INF), register-local
            #pragma unroll
            for (int k = 0; k < 8; ++k) {
                const int t = lane + (k << 6);
                if (t < n && (sr_mask & (1u << k))) {
                    if (t == cur_row) u_lds[t] += min_val;
                    else              u_lds[t] += min_val - shortest_lds[col4row_lds[t]];
                }
            }
            #pragma unroll
            for (int k = 0; k < 8; ++k) {
                if (((init_mask >> k) & 1) && vwork_r[k] == -INFINITY)
                    v_r[k] -= min_val - shortfin_r[k];
            }
            __syncthreads();

            if (lane == 0) {   // augment alternating path
                int j = sink_j;
                for (;;) {
                    const int ii = path_lds[j];
                    row4col_lds[j] = ii;
                    const int tmp = col4row_lds[ii];
                    col4row_lds[ii] = j;
                    j = tmp;
                    if (ii == cur_row) break;
                }
            }
            __syncthreads();
        }

        // refresh payloads (strided LDS reads, 2-way alias = free) and
        // reset per-row register state
        #pragma unroll
        for (int k = 0; k < 8; ++k) {
            const int j = lane + (k << 6);
            const bool valid = (init_mask >> k) & 1;
            pay_r[k] = valid ? (((unsigned)j << 10) | (unsigned)(row4col_lds[j] + 1))
                             : 0xFFFFFFFFu;
            vwork_r[k] = valid ? v_r[k] : -INFINITY;
            short_r[k] = INFINITY;
            shortfin_r[k] = INFINITY;
            path_r[k] = -1;
        }
        sr_mask = 0;
        __syncthreads();
    }

    for (int t = lane; t < n; t += 64)
        mapping[b * n + t] = col4row_lds[t];
}

// ---------------------------------------------------------------------------
// Phase 3: extrapolation (square problem => every row assigned; -1 guarded).
// ---------------------------------------------------------------------------
__global__ __launch_bounds__(256) void extrap_boxes_kernel(
    const float* __restrict__ p1_boxes, const float* __restrict__ p2_boxes,
    const float* __restrict__ toffs, const int* __restrict__ mapping,
    float* __restrict__ out_boxes)
{
    const int idx = blockIdx.x * blockDim.x + threadIdx.x;  // b*Mq + i
    if (idx >= Bq * Mq) return;
    const int b = idx / Mq;
    const float t0 = toffs[b * 3 + 0], t1 = toffs[b * 3 + 1], t2 = toffs[b * 3 + 2];
    const float factor = (t2 - t1) / (t1 - t0);
    const int m = mapping[idx];
    const float4 p2 = ((const float4*)p2_boxes)[idx];
    const float4 p1 = (m >= 0) ? ((const float4*)p1_boxes)[b * Nq + m] : p2;
    float4 o;
    o.x = p2.x + (p2.x - p1.x) * factor;
    o.y = p2.y + (p2.y - p1.y) * factor;
    o.z = fmaxf(p2.z + (p2.z - p1.z) * factor, 0.0f);
    o.w = fmaxf(p2.w + (p2.w - p1.w) * factor, 0.0f);
    ((float4*)out_boxes)[idx] = o;
}

__global__ __launch_bounds__(256) void extrap_logits_kernel(
    const float* __restrict__ p1_logits, const float* __restrict__ p2_logits,
    const int* __restrict__ mapping, float* __restrict__ out_logits)
{
    const int idx = blockIdx.x * blockDim.x + threadIdx.x;  // (b*Mq + i)*Cq + c
    if (idx >= Bq * Mq * Cq) return;
    const int c = idx % Cq;
    const int bi = idx / Cq;
    const int b = bi / Mq;
    const int m = mapping[bi];
    const float corr = (m >= 0) ? p1_logits[((size_t)b * Nq + m) * Cq + c] : 0.0f;
    out_logits[idx] = 0.5f * (p2_logits[idx] + corr);
}

// ---------------------------------------------------------------------------
extern "C" void kernel_launch(void* const* d_in, const int* in_sizes, int n_in,
                              void* d_out, int out_size, void* d_ws, size_t ws_size,
                              hipStream_t stream) {
    const float* p1_boxes  = (const float*)d_in[0];  // (B,N,4)
    const float* p1_logits = (const float*)d_in[1];  // (B,N,C)
    const float* p2_boxes  = (const float*)d_in[2];  // (B,M,4)
    const float* p2_logits = (const float*)d_in[3];  // (B,M,C)
    const float* toffs     = (const float*)d_in[4];  // (B,3)
    float* out = (float*)d_out;                      // boxes3 ++ logits3

    char* ws = (char*)d_ws;
    float* cost    = (float*)ws;                                   // 4 MB
    int*   mapping = (int*)  (ws + 4000000);                       // 8 KB
    float* v0      = (float*)(ws + 4008000);                       // 8 KB
    int*   amin    = (int*)  (ws + 4016000);                       // 8 KB

    dim3 cgrid((Nq + 15) / 16, (Mq + 15) / 16, Bq);
    cost_kernel<<<cgrid, 256, 0, stream>>>(p1_boxes, p1_logits, p2_boxes, p2_logits, cost);

    colred_kernel<<<dim3(2, Bq), 256, 0, stream>>>(cost, v0, amin);

    lsa_kernel<<<Bq, 64, 0, stream>>>(cost, v0, amin, mapping);

    extrap_boxes_kernel<<<(Bq * Mq + 255) / 256, 256, 0, stream>>>(
        p1_boxes, p2_boxes, toffs, mapping, out);
    extrap_logits_kernel<<<(Bq * Mq * Cq + 255) / 256, 256, 0, stream>>>(
        p1_logits, p2_logits, mapping, out + Bq * Mq * 4);
}

// Round 2
// 4506.811 us; speedup vs baseline: 1.3021x; 1.3021x over previous
//
#include <hip/hip_runtime.h>
#include <math.h>

#define Bq 4
#define Mq 500
#define Nq 500
#define Cq 91

// ---------------------------------------------------------------------------
// Phase 1: cost[b,i,j] = 0.5*||center2_i - center1_j||_2
//                      + 0.5*max_c |sigmoid(l2[i,c]) - sigmoid(l1[j,c])|
// ---------------------------------------------------------------------------
__device__ __forceinline__ float sigmoidf_(float x) {
    return 1.0f / (1.0f + expf(-x));
}

__global__ __launch_bounds__(256) void cost_kernel(
    const float* __restrict__ p1_boxes, const float* __restrict__ p1_logits,
    const float* __restrict__ p2_boxes, const float* __restrict__ p2_logits,
    float* __restrict__ cost)
{
    __shared__ float s2t[16][Cq + 1];   // stride 92 -> 2-way bank alias (free)
    __shared__ float s1t[16][Cq + 1];
    __shared__ float b2x[16], b2y[16], b1x[16], b1y[16];
    const int b  = blockIdx.z;
    const int i0 = blockIdx.y * 16;
    const int j0 = blockIdx.x * 16;
    const int tid = threadIdx.x;

    for (int t = tid; t < 16 * Cq; t += 256) {
        const int r = t / Cq, c = t - r * Cq;
        const int i = min(i0 + r, Mq - 1);
        const int j = min(j0 + r, Nq - 1);
        s2t[r][c] = sigmoidf_(p2_logits[((size_t)b * Mq + i) * Cq + c]);
        s1t[r][c] = sigmoidf_(p1_logits[((size_t)b * Nq + j) * Cq + c]);
    }
    if (tid < 16) {
        const int i = min(i0 + tid, Mq - 1);
        const int j = min(j0 + tid, Nq - 1);
        b2x[tid] = p2_boxes[((size_t)b * Mq + i) * 4 + 0];
        b2y[tid] = p2_boxes[((size_t)b * Mq + i) * 4 + 1];
        b1x[tid] = p1_boxes[((size_t)b * Nq + j) * 4 + 0];
        b1y[tid] = p1_boxes[((size_t)b * Nq + j) * 4 + 1];
    }
    __syncthreads();

    const int ty = tid >> 4, tx = tid & 15;
    const int i = i0 + ty, j = j0 + tx;
    if (i < Mq && j < Nq) {
        float mx = 0.0f;
        #pragma unroll 7
        for (int c = 0; c < Cq; ++c)
            mx = fmaxf(mx, fabsf(s2t[ty][c] - s1t[tx][c]));
        const float dx = b2x[ty] - b1x[tx];
        const float dy = b2y[ty] - b1y[tx];
        const float cd = sqrtf(dx * dx + dy * dy);
        cost[((size_t)b * Mq + i) * Nq + j] = 0.5f * cd + 0.5f * mx;
    }
}

// ---------------------------------------------------------------------------
// Phase 1.5: column reduction. v0[b][j] = min_i cost[b][i][j], amin = argmin.
// ---------------------------------------------------------------------------
__global__ __launch_bounds__(256) void colred_kernel(
    const float* __restrict__ cost, float* __restrict__ v0, int* __restrict__ amin)
{
    const int j = blockIdx.x * 256 + threadIdx.x;
    const int b = blockIdx.y;
    if (j >= Nq) return;
    const float* __restrict__ cb = cost + (size_t)b * Mq * Nq;
    float best = INFINITY;
    int bi = 0;
    #pragma unroll 4
    for (int i = 0; i < Mq; ++i) {
        const float c = cb[(size_t)i * Nq + j];
        if (c < best) { best = c; bi = i; }
    }
    v0[b * Nq + j] = best;
    amin[b * Nq + j] = bi;
}

// ---------------------------------------------------------------------------
// Fused (value, payload) wave64 argmin. Value flow is bit-identical to the
// proven wave_min_f32_ (same DPP controls, fminf accumulate into lane 63);
// the payload rides along each merge: wherever the min value propagates, its
// payload propagates. One 6-step chain replaces {f32 tree + readlane +
// equality-select + u32 tree + readlane}. Tie column choice can deviate from
// "lowest j" — harmless: optimum is unique (R1 ran a different trajectory,
// absmax 0.0 vs the fp64 reference).
// ---------------------------------------------------------------------------
template<int CTRL>
__device__ __forceinline__ void dppstep_(float& v, unsigned& p) {
    const float mv = __int_as_float(__builtin_amdgcn_update_dpp(
        0x7F800000, __float_as_int(v), CTRL, 0xF, 0xF, false));
    const unsigned mp = (unsigned)__builtin_amdgcn_update_dpp(
        (int)0xFFFFFFFFu, (int)p, CTRL, 0xF, 0xF, false);
    const bool le = (v <= mv);
    v = fminf(v, mv);
    p = le ? p : mp;
}
__device__ __forceinline__ void wave_argmin_(float& v, unsigned& p) {
    dppstep_<0x111>(v, p);   // row_shr:1
    dppstep_<0x112>(v, p);   // row_shr:2
    dppstep_<0x114>(v, p);   // row_shr:4
    dppstep_<0x118>(v, p);   // row_shr:8
    dppstep_<0x142>(v, p);   // row_bcast:15
    dppstep_<0x143>(v, p);   // row_bcast:31
    v = __int_as_float(__builtin_amdgcn_readlane(__float_as_int(v), 63));
    p = (unsigned)__builtin_amdgcn_readlane((int)p, 63);
}
__device__ __forceinline__ void pairmin_(float& va, unsigned& pa, float vb, unsigned pb) {
    const bool le = (va <= vb);
    va = fminf(va, vb);
    pa = le ? pa : pb;
}

// ---------------------------------------------------------------------------
// Phase 2: exact successive-shortest-path LAP (same unique optimum as the
// reference's LAPJV). One block = one batch, ONE wave.
//
// R2 ownership layout: lane L owns cols j = 4L+c (k=c, c=0..3) and
// j = 256+4L+c (k=4+c) -> the per-pop row read is 2x global_load_dwordx4
// instead of 8 scalar loads, and publish/refresh are ds_{read,write}_b128.
// valid cols: k<4 always; k>=4 iff lane<61 (j<500).
//
// R2 pop pipeline (latency-focused):
//   - fused (value,payload) DPP argmin: one 6-step chain -> {gmin, winner}.
//   - next-row loads issued IMMEDIATELY after the reduction (address clamped
//     on sink); poison, u_lds read, branch all hide in the load shadow.
//   - popped col k* poisoned on its owner lane: shortfin=short, short=+INF,
//     vwork=-INF (t=a-vwork=+INF => can't re-enter); v_r stays pristine.
// ---------------------------------------------------------------------------
__global__ __launch_bounds__(64) void lsa_kernel(
    const float* __restrict__ cost, const float* __restrict__ v0,
    const int* __restrict__ amin, int* __restrict__ mapping)
{
    constexpr int n = Nq;  // 500
    __shared__ float u_lds[512];
    __shared__ float shortest_lds[512];
    __shared__ int   path_lds[512];
    __shared__ int   row4col_lds[512];
    __shared__ int   col4row_lds[512];

    const int lane = threadIdx.x;
    const int b = blockIdx.x;
    const float* __restrict__ cb = cost + (size_t)b * n * n;

    // k<4 -> j = 4*lane+k ; k>=4 -> j = 256+4*lane+(k-4)
    const unsigned init_mask = (lane < 61) ? 0xFFu : 0x0Fu;
    const int off2 = (lane < 61) ? 256 + 4 * lane : 0;   // clamped 2nd-quad offset

    float v_r[8], vwork_r[8], short_r[8], shortfin_r[8];
    int path_r[8];
    unsigned pay_r[8];   // (j<<10) | (row4col[j]+1)

    // --- duals from column reduction ---
    {
        const float4 a0 = *(const float4*)(v0 + b * n + 4 * lane);
        const float4 a1 = *(const float4*)(v0 + b * n + off2);
        const float vv[8] = {a0.x, a0.y, a0.z, a0.w, a1.x, a1.y, a1.z, a1.w};
        #pragma unroll
        for (int k = 0; k < 8; ++k)
            v_r[k] = ((init_mask >> k) & 1) ? vv[k] : 0.0f;
    }
    for (int t = lane; t < n; t += 64)
        path_lds[t] = amin[b * n + t];            // stash argmins for lane0
    for (int t = lane; t < 512; t += 64) {
        u_lds[t] = 0.0f; row4col_lds[t] = -1; col4row_lds[t] = -1;
    }
    __syncthreads();
    if (lane == 0) {   // greedy matching on tight edges
        for (int j = 0; j < n; ++j) {
            const int i0 = path_lds[j];
            if (col4row_lds[i0] < 0) { col4row_lds[i0] = j; row4col_lds[j] = i0; }
        }
    }
    __syncthreads();
    {
        const int4 r0 = *(const int4*)&row4col_lds[4 * lane];
        const int4 r1 = *(const int4*)&row4col_lds[off2];
        const int rr[8] = {r0.x, r0.y, r0.z, r0.w, r1.x, r1.y, r1.z, r1.w};
        #pragma unroll
        for (int k = 0; k < 8; ++k) {
            const int j = (k < 4) ? 4 * lane + k : 256 + 4 * lane + (k - 4);
            const bool valid = (init_mask >> k) & 1;
            pay_r[k] = valid ? (((unsigned)j << 10) | (unsigned)(rr[k] + 1))
                             : 0xFFFFFFFFu;
            vwork_r[k] = valid ? v_r[k] : -INFINITY;
            short_r[k] = INFINITY;
            shortfin_r[k] = INFINITY;
            path_r[k] = -1;
        }
    }
    for (int t = lane; t < n; t += 64)
        path_lds[t] = -1;
    unsigned sr_mask = 0;
    __syncthreads();

    // --- successive shortest paths over free rows ---
    for (int cur_row = 0; cur_row < n; ++cur_row) {
        if (col4row_lds[cur_row] >= 0) continue;   // wave-uniform

        int sink_j = -1;
        int i = cur_row;
        float min_val = 0.0f;
        const float* __restrict__ crow = cb + (size_t)i * n;
        float4 cv0 = *(const float4*)(crow + 4 * lane);     // prologue loads
        float4 cv1 = *(const float4*)(crow + off2);
        float a = -u_lds[cur_row];                           // a = min_val - u[i]

        for (int pops = 0; pops < n; ++pops) {
            if ((i & 63) == lane) sr_mask |= 1u << (i >> 6);

            // relax with in-flight row (cv already issued last iteration)
            const float cvk[8] = {cv0.x, cv0.y, cv0.z, cv0.w,
                                  cv1.x, cv1.y, cv1.z, cv1.w};
            #pragma unroll
            for (int k = 0; k < 8; ++k) {
                const float r = cvk[k] + (a - vwork_r[k]);
                if (r < short_r[k]) { short_r[k] = r; path_r[k] = i; }
            }

            // fused local argmin tree (prefers lower k = lower j per lane)
            float    m0 = short_r[0], m1 = short_r[1], m2 = short_r[2], m3 = short_r[3];
            float    m4 = short_r[4], m5 = short_r[5], m6 = short_r[6], m7 = short_r[7];
            unsigned q0 = pay_r[0], q1 = pay_r[1], q2 = pay_r[2], q3 = pay_r[3];
            unsigned q4 = pay_r[4], q5 = pay_r[5], q6 = pay_r[6], q7 = pay_r[7];
            pairmin_(m0, q0, m1, q1);  pairmin_(m2, q2, m3, q3);
            pairmin_(m4, q4, m5, q5);  pairmin_(m6, q6, m7, q7);
            pairmin_(m0, q0, m2, q2);  pairmin_(m4, q4, m6, q6);
            pairmin_(m0, q0, m4, q4);
            wave_argmin_(m0, q0);                 // -> gmin, winner payload
            const float gmin = m0;
            const unsigned win = q0;

            min_val = gmin;
            const unsigned jst = win >> 10;
            const unsigned rc1 = win & 0x3FFu;

            // issue next-row loads EARLY (clamped on sink); bookkeeping hides
            const int i_next = (int)rc1 - 1;                 // -1 if sink
            const int i_safe = (i_next < 0) ? 0 : i_next;
            crow = cb + (size_t)i_safe * n;
            cv0 = *(const float4*)(crow + 4 * lane);
            cv1 = *(const float4*)(crow + off2);
            a = gmin - u_lds[i_safe];             // LDS read in load shadow

            // pop bookkeeping: poison winner col on its owner lane
            const int owner = (int)((jst >> 2) & 63u);
            const int kwin  = (int)(((jst >> 8) << 2) | (jst & 3u));
            #pragma unroll
            for (int k = 0; k < 8; ++k) {
                if (k == kwin && lane == owner) {
                    shortfin_r[k] = short_r[k];
                    short_r[k] = INFINITY;
                    vwork_r[k] = -INFINITY;
                }
            }

            if (rc1 == 0u) { sink_j = (int)jst; break; }
            i = i_next;
        }

        if (sink_j >= 0) {
            // publish final labels/path (vectorized; lanes 61-63's 2nd quad
            // lands in the unread 500..511 pad -> literal offset, NOT off2)
            *(float4*)&shortest_lds[4 * lane] =
                make_float4(shortfin_r[0], shortfin_r[1], shortfin_r[2], shortfin_r[3]);
            *(int4*)&path_lds[4 * lane] =
                make_int4(path_r[0], path_r[1], path_r[2], path_r[3]);
            *(float4*)&shortest_lds[256 + 4 * lane] =
                make_float4(shortfin_r[4], shortfin_r[5], shortfin_r[6], shortfin_r[7]);
            *(int4*)&path_lds[256 + 4 * lane] =
                make_int4(path_r[4], path_r[5], path_r[6], path_r[7]);
            __syncthreads();

            // u-update for SR rows (col4row read BEFORE augmentation);
            // v-update for scanned cols (marker: vwork == -INF), register-local
            #pragma unroll
            for (int k = 0; k < 8; ++k) {
                const int t = lane + (k << 6);
                if (t < n && (sr_mask & (1u << k))) {
                    if (t == cur_row) u_lds[t] += min_val;
                    else              u_lds[t] += min_val - shortest_lds[col4row_lds[t]];
                }
            }
            #pragma unroll
            for (int k = 0; k < 8; ++k) {
                if (((init_mask >> k) & 1) && vwork_r[k] == -INFINITY)
                    v_r[k] -= min_val - shortfin_r[k];
            }
            __syncthreads();

            if (lane == 0) {   // augment alternating path
                int j = sink_j;
                for (;;) {
                    const int ii = path_lds[j];
                    row4col_lds[j] = ii;
                    const int tmp = col4row_lds[ii];
                    col4row_lds[ii] = j;
                    j = tmp;
                    if (ii == cur_row) break;
                }
            }
            __syncthreads();
        }

        // refresh payloads (b128 LDS reads) and reset per-row register state
        {
            const int4 r0 = *(const int4*)&row4col_lds[4 * lane];
            const int4 r1 = *(const int4*)&row4col_lds[off2];
            const int rr[8] = {r0.x, r0.y, r0.z, r0.w, r1.x, r1.y, r1.z, r1.w};
            #pragma unroll
            for (int k = 0; k < 8; ++k) {
                const int j = (k < 4) ? 4 * lane + k : 256 + 4 * lane + (k - 4);
                const bool valid = (init_mask >> k) & 1;
                pay_r[k] = valid ? (((unsigned)j << 10) | (unsigned)(rr[k] + 1))
                                 : 0xFFFFFFFFu;
                vwork_r[k] = valid ? v_r[k] : -INFINITY;
                short_r[k] = INFINITY;
                shortfin_r[k] = INFINITY;
                path_r[k] = -1;
            }
        }
        sr_mask = 0;
        __syncthreads();
    }

    for (int t = lane; t < n; t += 64)
        mapping[b * n + t] = col4row_lds[t];
}

// ---------------------------------------------------------------------------
// Phase 3: extrapolation (square problem => every row assigned; -1 guarded).
// ---------------------------------------------------------------------------
__global__ __launch_bounds__(256) void extrap_boxes_kernel(
    const float* __restrict__ p1_boxes, const float* __restrict__ p2_boxes,
    const float* __restrict__ toffs, const int* __restrict__ mapping,
    float* __restrict__ out_boxes)
{
    const int idx = blockIdx.x * blockDim.x + threadIdx.x;  // b*Mq + i
    if (idx >= Bq * Mq) return;
    const int b = idx / Mq;
    const float t0 = toffs[b * 3 + 0], t1 = toffs[b * 3 + 1], t2 = toffs[b * 3 + 2];
    const float factor = (t2 - t1) / (t1 - t0);
    const int m = mapping[idx];
    const float4 p2 = ((const float4*)p2_boxes)[idx];
    const float4 p1 = (m >= 0) ? ((const float4*)p1_boxes)[b * Nq + m] : p2;
    float4 o;
    o.x = p2.x + (p2.x - p1.x) * factor;
    o.y = p2.y + (p2.y - p1.y) * factor;
    o.z = fmaxf(p2.z + (p2.z - p1.z) * factor, 0.0f);
    o.w = fmaxf(p2.w + (p2.w - p1.w) * factor, 0.0f);
    ((float4*)out_boxes)[idx] = o;
}

__global__ __launch_bounds__(256) void extrap_logits_kernel(
    const float* __restrict__ p1_logits, const float* __restrict__ p2_logits,
    const int* __restrict__ mapping, float* __restrict__ out_logits)
{
    const int idx = blockIdx.x * blockDim.x + threadIdx.x;  // (b*Mq + i)*Cq + c
    if (idx >= Bq * Mq * Cq) return;
    const int c = idx % Cq;
    const int bi = idx / Cq;
    const int b = bi / Mq;
    const int m = mapping[bi];
    const float corr = (m >= 0) ? p1_logits[((size_t)b * Nq + m) * Cq + c] : 0.0f;
    out_logits[idx] = 0.5f * (p2_logits[idx] + corr);
}

// ---------------------------------------------------------------------------
extern "C" void kernel_launch(void* const* d_in, const int* in_sizes, int n_in,
                              void* d_out, int out_size, void* d_ws, size_t ws_size,
                              hipStream_t stream) {
    const float* p1_boxes  = (const float*)d_in[0];  // (B,N,4)
    const float* p1_logits = (const float*)d_in[1];  // (B,N,C)
    const float* p2_boxes  = (const float*)d_in[2];  // (B,M,4)
    const float* p2_logits = (const float*)d_in[3];  // (B,M,C)
    const float* toffs     = (const float*)d_in[4];  // (B,3)
    float* out = (float*)d_out;                      // boxes3 ++ logits3

    char* ws = (char*)d_ws;
    float* cost    = (float*)ws;                                   // 4 MB
    int*   mapping = (int*)  (ws + 4000000);                       // 8 KB
    float* v0      = (float*)(ws + 4008000);                       // 8 KB
    int*   amin    = (int*)  (ws + 4016000);                       // 8 KB

    dim3 cgrid((Nq + 15) / 16, (Mq + 15) / 16, Bq);
    cost_kernel<<<cgrid, 256, 0, stream>>>(p1_boxes, p1_logits, p2_boxes, p2_logits, cost);

    colred_kernel<<<dim3(2, Bq), 256, 0, stream>>>(cost, v0, amin);

    lsa_kernel<<<Bq, 64, 0, stream>>>(cost, v0, amin, mapping);

    extrap_boxes_kernel<<<(Bq * Mq + 255) / 256, 256, 0, stream>>>(
        p1_boxes, p2_boxes, toffs, mapping, out);
    extrap_logits_kernel<<<(Bq * Mq * Cq + 255) / 256, 256, 0, stream>>>(
        p1_logits, p2_logits, mapping, out + Bq * Mq * 4);
}

// Round 3
// 4433.229 us; speedup vs baseline: 1.3237x; 1.0166x over previous
//
#include <hip/hip_runtime.h>
#include <math.h>

#define Bq 4
#define Mq 500
#define Nq 500
#define Cq 91

// ---------------------------------------------------------------------------
// Phase 1: cost[b,i,j] = 0.5*||center2_i - center1_j||_2
//                      + 0.5*max_c |sigmoid(l2[i,c]) - sigmoid(l1[j,c])|
// ---------------------------------------------------------------------------
__device__ __forceinline__ float sigmoidf_(float x) {
    return 1.0f / (1.0f + expf(-x));
}

__global__ __launch_bounds__(256) void cost_kernel(
    const float* __restrict__ p1_boxes, const float* __restrict__ p1_logits,
    const float* __restrict__ p2_boxes, const float* __restrict__ p2_logits,
    float* __restrict__ cost)
{
    __shared__ float s2t[16][Cq + 1];   // stride 92 -> 2-way bank alias (free)
    __shared__ float s1t[16][Cq + 1];
    __shared__ float b2x[16], b2y[16], b1x[16], b1y[16];
    const int b  = blockIdx.z;
    const int i0 = blockIdx.y * 16;
    const int j0 = blockIdx.x * 16;
    const int tid = threadIdx.x;

    for (int t = tid; t < 16 * Cq; t += 256) {
        const int r = t / Cq, c = t - r * Cq;
        const int i = min(i0 + r, Mq - 1);
        const int j = min(j0 + r, Nq - 1);
        s2t[r][c] = sigmoidf_(p2_logits[((size_t)b * Mq + i) * Cq + c]);
        s1t[r][c] = sigmoidf_(p1_logits[((size_t)b * Nq + j) * Cq + c]);
    }
    if (tid < 16) {
        const int i = min(i0 + tid, Mq - 1);
        const int j = min(j0 + tid, Nq - 1);
        b2x[tid] = p2_boxes[((size_t)b * Mq + i) * 4 + 0];
        b2y[tid] = p2_boxes[((size_t)b * Mq + i) * 4 + 1];
        b1x[tid] = p1_boxes[((size_t)b * Nq + j) * 4 + 0];
        b1y[tid] = p1_boxes[((size_t)b * Nq + j) * 4 + 1];
    }
    __syncthreads();

    const int ty = tid >> 4, tx = tid & 15;
    const int i = i0 + ty, j = j0 + tx;
    if (i < Mq && j < Nq) {
        float mx = 0.0f;
        #pragma unroll 7
        for (int c = 0; c < Cq; ++c)
            mx = fmaxf(mx, fabsf(s2t[ty][c] - s1t[tx][c]));
        const float dx = b2x[ty] - b1x[tx];
        const float dy = b2y[ty] - b1y[tx];
        const float cd = sqrtf(dx * dx + dy * dy);
        cost[((size_t)b * Mq + i) * Nq + j] = 0.5f * cd + 0.5f * mx;
    }
}

// ---------------------------------------------------------------------------
// Phase 1.5: column reduction. v0[b][j] = min_i cost[b][i][j], amin = argmin.
// ---------------------------------------------------------------------------
__global__ __launch_bounds__(256) void colred_kernel(
    const float* __restrict__ cost, float* __restrict__ v0, int* __restrict__ amin)
{
    const int j = blockIdx.x * 256 + threadIdx.x;
    const int b = blockIdx.y;
    if (j >= Nq) return;
    const float* __restrict__ cb = cost + (size_t)b * Mq * Nq;
    float best = INFINITY;
    int bi = 0;
    #pragma unroll 4
    for (int i = 0; i < Mq; ++i) {
        const float c = cb[(size_t)i * Nq + j];
        if (c < best) { best = c; bi = i; }
    }
    v0[b * Nq + j] = best;
    amin[b * Nq + j] = bi;
}

// ---------------------------------------------------------------------------
// Value-only wave64 min (v_min_f32_dpp single instr per step) — used where
// no payload is needed (reduction transfer).
// ---------------------------------------------------------------------------
template<int CTRL>
__device__ __forceinline__ float dppminv_(float x) {
    const int moved = __builtin_amdgcn_update_dpp(
        0x7F800000, __float_as_int(x), CTRL, 0xF, 0xF, false);
    return fminf(x, __int_as_float(moved));
}
__device__ __forceinline__ float wave_min_f32_(float x) {
    x = dppminv_<0x111>(x);
    x = dppminv_<0x112>(x);
    x = dppminv_<0x114>(x);
    x = dppminv_<0x118>(x);
    x = dppminv_<0x142>(x);
    x = dppminv_<0x143>(x);
    return __int_as_float(__builtin_amdgcn_readlane(__float_as_int(x), 63));
}

// ---------------------------------------------------------------------------
// Fused (value, payload) wave64 argmin. Value flow is bit-identical to
// wave_min_f32_ (same DPP controls, fminf accumulate into lane 63); the
// payload rides along each merge. Tie column choice can deviate from
// "lowest j" — harmless: optimum is unique (absmax 0.0 across several
// different trajectories).
// ---------------------------------------------------------------------------
template<int CTRL>
__device__ __forceinline__ void dppstep_(float& v, unsigned& p) {
    const float mv = __int_as_float(__builtin_amdgcn_update_dpp(
        0x7F800000, __float_as_int(v), CTRL, 0xF, 0xF, false));
    const unsigned mp = (unsigned)__builtin_amdgcn_update_dpp(
        (int)0xFFFFFFFFu, (int)p, CTRL, 0xF, 0xF, false);
    const bool le = (v <= mv);
    v = fminf(v, mv);
    p = le ? p : mp;
}
__device__ __forceinline__ void wave_argmin_(float& v, unsigned& p) {
    dppstep_<0x111>(v, p);   // row_shr:1
    dppstep_<0x112>(v, p);   // row_shr:2
    dppstep_<0x114>(v, p);   // row_shr:4
    dppstep_<0x118>(v, p);   // row_shr:8
    dppstep_<0x142>(v, p);   // row_bcast:15
    dppstep_<0x143>(v, p);   // row_bcast:31
    v = __int_as_float(__builtin_amdgcn_readlane(__float_as_int(v), 63));
    p = (unsigned)__builtin_amdgcn_readlane((int)p, 63);
}
__device__ __forceinline__ void pairmin_(float& va, unsigned& pa, float vb, unsigned pb) {
    const bool le = (va <= vb);
    va = fminf(va, vb);
    pa = le ? pa : pb;
}

// ---------------------------------------------------------------------------
// Phase 2: exact successive-shortest-path LAP (same unique optimum as the
// reference's LAPJV). One block = one batch, ONE wave.
//
// Ownership layout: lane L owns cols j = 4L+c (k=c, c=0..3) and
// j = 256+4L+c (k=4+c) -> per-pop row read = 2x global_load_dwordx4.
// valid cols: k<4 always; k>=4 iff lane<61 (j<500).
//
// R3: JV reduction TRANSFER added between greedy matching and SSP
// (wave-parallel scan per assigned row; sequential-v JV semantics).
// Matched cols are distinct => each row's v[j1] is untouched until its own
// turn => matched edges stay tight; mu is a min over the row => c-u-v >= 0
// everywhere. SSP over feasible+tight state = exact optimum. Effect: slack
// moves into u of matched rows, so Dijkstra stops wasting pops crawling
// matched columns and reaches free columns (sinks) sooner.
//
// Pop pipeline (R2, proven): fused DPP argmin; next-row loads issued
// immediately after the reduction (clamped on sink); poison & bookkeeping
// hide in the load shadow.
// ---------------------------------------------------------------------------
__global__ __launch_bounds__(64) void lsa_kernel(
    const float* __restrict__ cost, const float* __restrict__ v0,
    const int* __restrict__ amin, int* __restrict__ mapping)
{
    constexpr int n = Nq;  // 500
    __shared__ float u_lds[512];
    __shared__ float shortest_lds[512];
    __shared__ int   path_lds[512];
    __shared__ int   row4col_lds[512];
    __shared__ int   col4row_lds[512];

    const int lane = threadIdx.x;
    const int b = blockIdx.x;
    const float* __restrict__ cb = cost + (size_t)b * n * n;

    // k<4 -> j = 4*lane+k ; k>=4 -> j = 256+4*lane+(k-4)
    const unsigned init_mask = (lane < 61) ? 0xFFu : 0x0Fu;
    const int off2 = (lane < 61) ? 256 + 4 * lane : 0;   // clamped 2nd-quad offset

    float v_r[8], vwork_r[8], short_r[8], shortfin_r[8];
    int path_r[8];
    unsigned pay_r[8];   // (j<<10) | (row4col[j]+1)

    // --- duals from column reduction ---
    {
        const float4 a0 = *(const float4*)(v0 + b * n + 4 * lane);
        const float4 a1 = *(const float4*)(v0 + b * n + off2);
        const float vv[8] = {a0.x, a0.y, a0.z, a0.w, a1.x, a1.y, a1.z, a1.w};
        #pragma unroll
        for (int k = 0; k < 8; ++k)
            v_r[k] = ((init_mask >> k) & 1) ? vv[k] : 0.0f;
    }
    for (int t = lane; t < n; t += 64)
        path_lds[t] = amin[b * n + t];            // stash argmins for lane0
    for (int t = lane; t < 512; t += 64) {
        u_lds[t] = 0.0f; row4col_lds[t] = -1; col4row_lds[t] = -1;
    }
    __syncthreads();
    if (lane == 0) {   // greedy matching on tight edges
        for (int j = 0; j < n; ++j) {
            const int i0 = path_lds[j];
            if (col4row_lds[i0] < 0) { col4row_lds[i0] = j; row4col_lds[j] = i0; }
        }
    }
    __syncthreads();

    // --- JV reduction transfer (wave-parallel row scans, value-only DPP) ---
    for (int i2 = 0; i2 < n; ++i2) {
        const int j1 = col4row_lds[i2];            // uniform broadcast read
        if (j1 < 0) continue;                      // free row
        const float* __restrict__ crow = cb + (size_t)i2 * n;
        const float4 c0 = *(const float4*)(crow + 4 * lane);
        const float4 c1 = *(const float4*)(crow + off2);
        const float cc[8] = {c0.x, c0.y, c0.z, c0.w, c1.x, c1.y, c1.z, c1.w};
        const int owner = (j1 >> 2) & 63;          // wave-uniform
        const int kwin  = ((j1 >> 8) << 2) | (j1 & 3);
        float d[8];
        #pragma unroll
        for (int k = 0; k < 8; ++k) {
            const bool use = ((init_mask >> k) & 1) && !(k == kwin && lane == owner);
            d[k] = use ? cc[k] - v_r[k] : INFINITY;
        }
        const float mu = wave_min_f32_(
            fminf(fminf(fminf(d[0], d[1]), fminf(d[2], d[3])),
                  fminf(fminf(d[4], d[5]), fminf(d[6], d[7]))));
        #pragma unroll
        for (int k = 0; k < 8; ++k)
            if (k == kwin && lane == owner) v_r[k] -= mu;
        if (lane == 0) u_lds[i2] = mu;
    }
    __syncthreads();

    {
        const int4 r0 = *(const int4*)&row4col_lds[4 * lane];
        const int4 r1 = *(const int4*)&row4col_lds[off2];
        const int rr[8] = {r0.x, r0.y, r0.z, r0.w, r1.x, r1.y, r1.z, r1.w};
        #pragma unroll
        for (int k = 0; k < 8; ++k) {
            const int j = (k < 4) ? 4 * lane + k : 256 + 4 * lane + (k - 4);
            const bool valid = (init_mask >> k) & 1;
            pay_r[k] = valid ? (((unsigned)j << 10) | (unsigned)(rr[k] + 1))
                             : 0xFFFFFFFFu;
            vwork_r[k] = valid ? v_r[k] : -INFINITY;
            short_r[k] = INFINITY;
            shortfin_r[k] = INFINITY;
            path_r[k] = -1;
        }
    }
    for (int t = lane; t < n; t += 64)
        path_lds[t] = -1;
    unsigned sr_mask = 0;
    __syncthreads();

    // --- successive shortest paths over free rows ---
    for (int cur_row = 0; cur_row < n; ++cur_row) {
        if (col4row_lds[cur_row] >= 0) continue;   // wave-uniform

        int sink_j = -1;
        int i = cur_row;
        float min_val = 0.0f;
        const float* __restrict__ crow = cb + (size_t)i * n;
        float4 cv0 = *(const float4*)(crow + 4 * lane);     // prologue loads
        float4 cv1 = *(const float4*)(crow + off2);
        float a = -u_lds[cur_row];                           // a = min_val - u[i]

        for (int pops = 0; pops < n; ++pops) {
            if ((i & 63) == lane) sr_mask |= 1u << (i >> 6);

            // relax with in-flight row (cv already issued last iteration)
            const float cvk[8] = {cv0.x, cv0.y, cv0.z, cv0.w,
                                  cv1.x, cv1.y, cv1.z, cv1.w};
            #pragma unroll
            for (int k = 0; k < 8; ++k) {
                const float r = cvk[k] + (a - vwork_r[k]);
                if (r < short_r[k]) { short_r[k] = r; path_r[k] = i; }
            }

            // fused local argmin tree (prefers lower k = lower j per lane)
            float    m0 = short_r[0], m1 = short_r[1], m2 = short_r[2], m3 = short_r[3];
            float    m4 = short_r[4], m5 = short_r[5], m6 = short_r[6], m7 = short_r[7];
            unsigned q0 = pay_r[0], q1 = pay_r[1], q2 = pay_r[2], q3 = pay_r[3];
            unsigned q4 = pay_r[4], q5 = pay_r[5], q6 = pay_r[6], q7 = pay_r[7];
            pairmin_(m0, q0, m1, q1);  pairmin_(m2, q2, m3, q3);
            pairmin_(m4, q4, m5, q5);  pairmin_(m6, q6, m7, q7);
            pairmin_(m0, q0, m2, q2);  pairmin_(m4, q4, m6, q6);
            pairmin_(m0, q0, m4, q4);
            wave_argmin_(m0, q0);                 // -> gmin, winner payload
            const float gmin = m0;
            const unsigned win = q0;

            min_val = gmin;
            const unsigned jst = win >> 10;
            const unsigned rc1 = win & 0x3FFu;

            // issue next-row loads EARLY (clamped on sink); bookkeeping hides
            const int i_next = (int)rc1 - 1;                 // -1 if sink
            const int i_safe = (i_next < 0) ? 0 : i_next;
            crow = cb + (size_t)i_safe * n;
            cv0 = *(const float4*)(crow + 4 * lane);
            cv1 = *(const float4*)(crow + off2);
            a = gmin - u_lds[i_safe];             // LDS read in load shadow

            // pop bookkeeping: poison winner col on its owner lane
            const int owner = (int)((jst >> 2) & 63u);
            const int kwin  = (int)(((jst >> 8) << 2) | (jst & 3u));
            #pragma unroll
            for (int k = 0; k < 8; ++k) {
                if (k == kwin && lane == owner) {
                    shortfin_r[k] = short_r[k];
                    short_r[k] = INFINITY;
                    vwork_r[k] = -INFINITY;
                }
            }

            if (rc1 == 0u) { sink_j = (int)jst; break; }
            i = i_next;
        }

        if (sink_j >= 0) {
            // publish final labels/path (vectorized; lanes 61-63's 2nd quad
            // lands in the unread 500..511 pad -> literal offset, NOT off2)
            *(float4*)&shortest_lds[4 * lane] =
                make_float4(shortfin_r[0], shortfin_r[1], shortfin_r[2], shortfin_r[3]);
            *(int4*)&path_lds[4 * lane] =
                make_int4(path_r[0], path_r[1], path_r[2], path_r[3]);
            *(float4*)&shortest_lds[256 + 4 * lane] =
                make_float4(shortfin_r[4], shortfin_r[5], shortfin_r[6], shortfin_r[7]);
            *(int4*)&path_lds[256 + 4 * lane] =
                make_int4(path_r[4], path_r[5], path_r[6], path_r[7]);
            __syncthreads();

            // u-update for SR rows (col4row read BEFORE augmentation);
            // v-update for scanned cols (marker: vwork == -INF), register-local
            #pragma unroll
            for (int k = 0; k < 8; ++k) {
                const int t = lane + (k << 6);
                if (t < n && (sr_mask & (1u << k))) {
                    if (t == cur_row) u_lds[t] += min_val;
                    else              u_lds[t] += min_val - shortest_lds[col4row_lds[t]];
                }
            }
            #pragma unroll
            for (int k = 0; k < 8; ++k) {
                if (((init_mask >> k) & 1) && vwork_r[k] == -INFINITY)
                    v_r[k] -= min_val - shortfin_r[k];
            }
            __syncthreads();

            if (lane == 0) {   // augment alternating path
                int j = sink_j;
                for (;;) {
                    const int ii = path_lds[j];
                    row4col_lds[j] = ii;
                    const int tmp = col4row_lds[ii];
                    col4row_lds[ii] = j;
                    j = tmp;
                    if (ii == cur_row) break;
                }
            }
            __syncthreads();
        }

        // refresh payloads (b128 LDS reads) and reset per-row register state
        {
            const int4 r0 = *(const int4*)&row4col_lds[4 * lane];
            const int4 r1 = *(const int4*)&row4col_lds[off2];
            const int rr[8] = {r0.x, r0.y, r0.z, r0.w, r1.x, r1.y, r1.z, r1.w};
            #pragma unroll
            for (int k = 0; k < 8; ++k) {
                const int j = (k < 4) ? 4 * lane + k : 256 + 4 * lane + (k - 4);
                const bool valid = (init_mask >> k) & 1;
                pay_r[k] = valid ? (((unsigned)j << 10) | (unsigned)(rr[k] + 1))
                                 : 0xFFFFFFFFu;
                vwork_r[k] = valid ? v_r[k] : -INFINITY;
                short_r[k] = INFINITY;
                shortfin_r[k] = INFINITY;
                path_r[k] = -1;
            }
        }
        sr_mask = 0;
        __syncthreads();
    }

    for (int t = lane; t < n; t += 64)
        mapping[b * n + t] = col4row_lds[t];
}

// ---------------------------------------------------------------------------
// Phase 3: extrapolation (square problem => every row assigned; -1 guarded).
// ---------------------------------------------------------------------------
__global__ __launch_bounds__(256) void extrap_boxes_kernel(
    const float* __restrict__ p1_boxes, const float* __restrict__ p2_boxes,
    const float* __restrict__ toffs, const int* __restrict__ mapping,
    float* __restrict__ out_boxes)
{
    const int idx = blockIdx.x * blockDim.x + threadIdx.x;  // b*Mq + i
    if (idx >= Bq * Mq) return;
    const int b = idx / Mq;
    const float t0 = toffs[b * 3 + 0], t1 = toffs[b * 3 + 1], t2 = toffs[b * 3 + 2];
    const float factor = (t2 - t1) / (t1 - t0);
    const int m = mapping[idx];
    const float4 p2 = ((const float4*)p2_boxes)[idx];
    const float4 p1 = (m >= 0) ? ((const float4*)p1_boxes)[b * Nq + m] : p2;
    float4 o;
    o.x = p2.x + (p2.x - p1.x) * factor;
    o.y = p2.y + (p2.y - p1.y) * factor;
    o.z = fmaxf(p2.z + (p2.z - p1.z) * factor, 0.0f);
    o.w = fmaxf(p2.w + (p2.w - p1.w) * factor, 0.0f);
    ((float4*)out_boxes)[idx] = o;
}

__global__ __launch_bounds__(256) void extrap_logits_kernel(
    const float* __restrict__ p1_logits, const float* __restrict__ p2_logits,
    const int* __restrict__ mapping, float* __restrict__ out_logits)
{
    const int idx = blockIdx.x * blockDim.x + threadIdx.x;  // (b*Mq + i)*Cq + c
    if (idx >= Bq * Mq * Cq) return;
    const int c = idx % Cq;
    const int bi = idx / Cq;
    const int b = bi / Mq;
    const int m = mapping[bi];
    const float corr = (m >= 0) ? p1_logits[((size_t)b * Nq + m) * Cq + c] : 0.0f;
    out_logits[idx] = 0.5f * (p2_logits[idx] + corr);
}

// ---------------------------------------------------------------------------
extern "C" void kernel_launch(void* const* d_in, const int* in_sizes, int n_in,
                              void* d_out, int out_size, void* d_ws, size_t ws_size,
                              hipStream_t stream) {
    const float* p1_boxes  = (const float*)d_in[0];  // (B,N,4)
    const float* p1_logits = (const float*)d_in[1];  // (B,N,C)
    const float* p2_boxes  = (const float*)d_in[2];  // (B,M,4)
    const float* p2_logits = (const float*)d_in[3];  // (B,M,C)
    const float* toffs     = (const float*)d_in[4];  // (B,3)
    float* out = (float*)d_out;                      // boxes3 ++ logits3

    char* ws = (char*)d_ws;
    float* cost    = (float*)ws;                                   // 4 MB
    int*   mapping = (int*)  (ws + 4000000);                       // 8 KB
    float* v0      = (float*)(ws + 4008000);                       // 8 KB
    int*   amin    = (int*)  (ws + 4016000);                       // 8 KB

    dim3 cgrid((Nq + 15) / 16, (Mq + 15) / 16, Bq);
    cost_kernel<<<cgrid, 256, 0, stream>>>(p1_boxes, p1_logits, p2_boxes, p2_logits, cost);

    colred_kernel<<<dim3(2, Bq), 256, 0, stream>>>(cost, v0, amin);

    lsa_kernel<<<Bq, 64, 0, stream>>>(cost, v0, amin, mapping);

    extrap_boxes_kernel<<<(Bq * Mq + 255) / 256, 256, 0, stream>>>(
        p1_boxes, p2_boxes, toffs, mapping, out);
    extrap_logits_kernel<<<(Bq * Mq * Cq + 255) / 256, 256, 0, stream>>>(
        p1_logits, p2_logits, mapping, out + Bq * Mq * 4);
}

// Round 4
// 4210.638 us; speedup vs baseline: 1.3936x; 1.0529x over previous
//
#include <hip/hip_runtime.h>
#include <math.h>

#define Bq 4
#define Mq 500
#define Nq 500
#define Cq 91

// ---------------------------------------------------------------------------
// Phase 1: cost[b,i,j] = 0.5*||center2_i - center1_j||_2
//                      + 0.5*max_c |sigmoid(l2[i,c]) - sigmoid(l1[j,c])|
// ---------------------------------------------------------------------------
__device__ __forceinline__ float sigmoidf_(float x) {
    return 1.0f / (1.0f + expf(-x));
}

__global__ __launch_bounds__(256) void cost_kernel(
    const float* __restrict__ p1_boxes, const float* __restrict__ p1_logits,
    const float* __restrict__ p2_boxes, const float* __restrict__ p2_logits,
    float* __restrict__ cost)
{
    __shared__ float s2t[16][Cq + 1];   // stride 92 -> 2-way bank alias (free)
    __shared__ float s1t[16][Cq + 1];
    __shared__ float b2x[16], b2y[16], b1x[16], b1y[16];
    const int b  = blockIdx.z;
    const int i0 = blockIdx.y * 16;
    const int j0 = blockIdx.x * 16;
    const int tid = threadIdx.x;

    for (int t = tid; t < 16 * Cq; t += 256) {
        const int r = t / Cq, c = t - r * Cq;
        const int i = min(i0 + r, Mq - 1);
        const int j = min(j0 + r, Nq - 1);
        s2t[r][c] = sigmoidf_(p2_logits[((size_t)b * Mq + i) * Cq + c]);
        s1t[r][c] = sigmoidf_(p1_logits[((size_t)b * Nq + j) * Cq + c]);
    }
    if (tid < 16) {
        const int i = min(i0 + tid, Mq - 1);
        const int j = min(j0 + tid, Nq - 1);
        b2x[tid] = p2_boxes[((size_t)b * Mq + i) * 4 + 0];
        b2y[tid] = p2_boxes[((size_t)b * Mq + i) * 4 + 1];
        b1x[tid] = p1_boxes[((size_t)b * Nq + j) * 4 + 0];
        b1y[tid] = p1_boxes[((size_t)b * Nq + j) * 4 + 1];
    }
    __syncthreads();

    const int ty = tid >> 4, tx = tid & 15;
    const int i = i0 + ty, j = j0 + tx;
    if (i < Mq && j < Nq) {
        float mx = 0.0f;
        #pragma unroll 7
        for (int c = 0; c < Cq; ++c)
            mx = fmaxf(mx, fabsf(s2t[ty][c] - s1t[tx][c]));
        const float dx = b2x[ty] - b1x[tx];
        const float dy = b2y[ty] - b1y[tx];
        const float cd = sqrtf(dx * dx + dy * dy);
        cost[((size_t)b * Mq + i) * Nq + j] = 0.5f * cd + 0.5f * mx;
    }
}

// ---------------------------------------------------------------------------
// Phase 1.5: column reduction. v0[b][j] = min_i cost[b][i][j], amin = argmin.
// ---------------------------------------------------------------------------
__global__ __launch_bounds__(256) void colred_kernel(
    const float* __restrict__ cost, float* __restrict__ v0, int* __restrict__ amin)
{
    const int j = blockIdx.x * 256 + threadIdx.x;
    const int b = blockIdx.y;
    if (j >= Nq) return;
    const float* __restrict__ cb = cost + (size_t)b * Mq * Nq;
    float best = INFINITY;
    int bi = 0;
    #pragma unroll 4
    for (int i = 0; i < Mq; ++i) {
        const float c = cb[(size_t)i * Nq + j];
        if (c < best) { best = c; bi = i; }
    }
    v0[b * Nq + j] = best;
    amin[b * Nq + j] = bi;
}

// ---------------------------------------------------------------------------
// Value-only wave64 min: 6 x v_min_f32_dpp (single instr/step) + readlane.
// min over floats (no NaN, no -0 here) is associative => result bit-exact
// regardless of reduction order — identical gmin to any other min tree.
// ---------------------------------------------------------------------------
template<int CTRL>
__device__ __forceinline__ float dppminv_(float x) {
    const int moved = __builtin_amdgcn_update_dpp(
        0x7F800000, __float_as_int(x), CTRL, 0xF, 0xF, false);
    return fminf(x, __int_as_float(moved));
}
__device__ __forceinline__ float wave_min_f32_(float x) {
    x = dppminv_<0x111>(x);
    x = dppminv_<0x112>(x);
    x = dppminv_<0x114>(x);
    x = dppminv_<0x118>(x);
    x = dppminv_<0x142>(x);
    x = dppminv_<0x143>(x);
    return __int_as_float(__builtin_amdgcn_readlane(__float_as_int(x), 63));
}

// local fused (value,payload) merge — cmp + min + cndmask
__device__ __forceinline__ void pairmin_(float& va, unsigned& pa, float vb, unsigned pb) {
    const bool le = (va <= vb);
    va = fminf(va, vb);
    pa = le ? pa : pb;
}

// ---------------------------------------------------------------------------
// Phase 2: exact successive-shortest-path LAP (same unique optimum as the
// reference's LAPJV). One block = one batch, ONE wave.
//
// Ownership layout: lane L owns cols j = 4L+c (k=c, c=0..3) and
// j = 256+4L+c (k=4+c) -> per-pop row read = 2x global_load_dwordx4.
// valid cols: k<4 always; k>=4 iff lane<61 (j<500).
//
// R4 wave argmin (latency-minimized):
//   local fused pairmin tree -> (lmin, lpay); value-only DPP min -> gmin
//   (bit-exact, drives all duals exactly as before); then owner lane via
//   __ballot(lmin==gmin) + ctz, payload via dynamic v_readlane. Replaces
//   the 6-step fused (value,payload) DPP chain (~5 instr & ~12cy per step)
//   with 6 single v_min_f32_dpp + 3 cheap ops. Tie COLUMN choice may
//   differ — benign (unique optimum; tie-break changed in R2, absmax 0.0).
//
// Pop pipeline (R2, proven): next-row loads issued immediately after the
// reduction (clamped on sink); poison/bookkeeping/t_r hide in load shadow;
// relax split quad0/quad1 so quad0 can start at vmcnt(1).
// ---------------------------------------------------------------------------
__global__ __launch_bounds__(64) void lsa_kernel(
    const float* __restrict__ cost, const float* __restrict__ v0,
    const int* __restrict__ amin, int* __restrict__ mapping)
{
    constexpr int n = Nq;  // 500
    __shared__ float u_lds[512];
    __shared__ float shortest_lds[512];
    __shared__ int   path_lds[512];
    __shared__ int   row4col_lds[512];
    __shared__ int   col4row_lds[512];

    const int lane = threadIdx.x;
    const int b = blockIdx.x;
    const float* __restrict__ cb = cost + (size_t)b * n * n;

    // k<4 -> j = 4*lane+k ; k>=4 -> j = 256+4*lane+(k-4)
    const unsigned init_mask = (lane < 61) ? 0xFFu : 0x0Fu;
    const int off2 = (lane < 61) ? 256 + 4 * lane : 0;   // clamped 2nd-quad offset

    float v_r[8], vwork_r[8], short_r[8], shortfin_r[8], t_r[8];
    int path_r[8];
    unsigned pay_r[8];   // (j<<10) | (row4col[j]+1)

    // --- duals from column reduction ---
    {
        const float4 a0 = *(const float4*)(v0 + b * n + 4 * lane);
        const float4 a1 = *(const float4*)(v0 + b * n + off2);
        const float vv[8] = {a0.x, a0.y, a0.z, a0.w, a1.x, a1.y, a1.z, a1.w};
        #pragma unroll
        for (int k = 0; k < 8; ++k)
            v_r[k] = ((init_mask >> k) & 1) ? vv[k] : 0.0f;
    }
    for (int t = lane; t < n; t += 64)
        path_lds[t] = amin[b * n + t];            // stash argmins for lane0
    for (int t = lane; t < 512; t += 64) {
        u_lds[t] = 0.0f; row4col_lds[t] = -1; col4row_lds[t] = -1;
    }
    __syncthreads();
    if (lane == 0) {   // greedy matching on tight edges
        for (int j = 0; j < n; ++j) {
            const int i0 = path_lds[j];
            if (col4row_lds[i0] < 0) { col4row_lds[i0] = j; row4col_lds[j] = i0; }
        }
    }
    __syncthreads();

    // --- JV reduction transfer (R3, kept: pays for itself), now software-
    // pipelined: row i2+1's loads + col4row read issue before processing i2,
    // so the ~200cy L2 latency hides under the previous iteration's VALU ---
    {
        int j1c = col4row_lds[0];
        float4 ta0 = *(const float4*)(cb + 4 * lane);
        float4 ta1 = *(const float4*)(cb + off2);
        for (int i2 = 0; i2 < n; ++i2) {
            const float4 c0 = ta0, c1 = ta1;
            const int j1 = j1c;
            const int inx = (i2 + 1 < n) ? i2 + 1 : i2;
            const float* __restrict__ crn = cb + (size_t)inx * n;
            ta0 = *(const float4*)(crn + 4 * lane);
            ta1 = *(const float4*)(crn + off2);
            j1c = col4row_lds[inx];
            if (j1 < 0) continue;                  // free row: no transfer
            const float cc[8] = {c0.x, c0.y, c0.z, c0.w, c1.x, c1.y, c1.z, c1.w};
            const int owner = (j1 >> 2) & 63;      // wave-uniform
            const int kwin  = ((j1 >> 8) << 2) | (j1 & 3);
            float d[8];
            #pragma unroll
            for (int k = 0; k < 8; ++k) {
                const bool use = ((init_mask >> k) & 1) && !(k == kwin && lane == owner);
                d[k] = use ? cc[k] - v_r[k] : INFINITY;
            }
            const float mu = wave_min_f32_(
                fminf(fminf(fminf(d[0], d[1]), fminf(d[2], d[3])),
                      fminf(fminf(d[4], d[5]), fminf(d[6], d[7]))));
            #pragma unroll
            for (int k = 0; k < 8; ++k)
                if (k == kwin && lane == owner) v_r[k] -= mu;
            if (lane == 0) u_lds[i2] = mu;
        }
    }
    __syncthreads();

    {
        const int4 r0 = *(const int4*)&row4col_lds[4 * lane];
        const int4 r1 = *(const int4*)&row4col_lds[off2];
        const int rr[8] = {r0.x, r0.y, r0.z, r0.w, r1.x, r1.y, r1.z, r1.w};
        #pragma unroll
        for (int k = 0; k < 8; ++k) {
            const int j = (k < 4) ? 4 * lane + k : 256 + 4 * lane + (k - 4);
            const bool valid = (init_mask >> k) & 1;
            pay_r[k] = valid ? (((unsigned)j << 10) | (unsigned)(rr[k] + 1))
                             : 0xFFFFFFFFu;
            vwork_r[k] = valid ? v_r[k] : -INFINITY;
            short_r[k] = INFINITY;
            shortfin_r[k] = INFINITY;
            path_r[k] = -1;
        }
    }
    for (int t = lane; t < n; t += 64)
        path_lds[t] = -1;
    unsigned sr_mask = 0;
    __syncthreads();

    // --- successive shortest paths over free rows ---
    for (int cur_row = 0; cur_row < n; ++cur_row) {
        if (col4row_lds[cur_row] >= 0) continue;   // wave-uniform

        int sink_j = -1;
        int i = cur_row;
        float min_val = 0.0f;
        const float* __restrict__ crow = cb + (size_t)i * n;
        float4 cv0 = *(const float4*)(crow + 4 * lane);     // prologue loads
        float4 cv1 = *(const float4*)(crow + off2);
        float a = -u_lds[cur_row];                           // a = min_val - u[i]

        for (int pops = 0; pops < n; ++pops) {
            if ((i & 63) == lane) sr_mask |= 1u << (i >> 6);

            // t_r fills the load shadow (a known since last reduction)
            #pragma unroll
            for (int k = 0; k < 8; ++k) t_r[k] = a - vwork_r[k];

            // relax quad0 (cv0) then quad1 (cv1): quad0 can start at vmcnt(1)
            {
                const float c4[4] = {cv0.x, cv0.y, cv0.z, cv0.w};
                #pragma unroll
                for (int k = 0; k < 4; ++k) {
                    const float r = c4[k] + t_r[k];
                    if (r < short_r[k]) { short_r[k] = r; path_r[k] = i; }
                }
            }
            {
                const float c4[4] = {cv1.x, cv1.y, cv1.z, cv1.w};
                #pragma unroll
                for (int k = 0; k < 4; ++k) {
                    const float r = c4[k] + t_r[4 + k];
                    if (r < short_r[4 + k]) { short_r[4 + k] = r; path_r[4 + k] = i; }
                }
            }

            // fused local argmin tree (prefers lower k = lower j per lane)
            float    m0 = short_r[0], m1 = short_r[1], m2 = short_r[2], m3 = short_r[3];
            float    m4 = short_r[4], m5 = short_r[5], m6 = short_r[6], m7 = short_r[7];
            unsigned q0 = pay_r[0], q1 = pay_r[1], q2 = pay_r[2], q3 = pay_r[3];
            unsigned q4 = pay_r[4], q5 = pay_r[5], q6 = pay_r[6], q7 = pay_r[7];
            pairmin_(m0, q0, m1, q1);  pairmin_(m2, q2, m3, q3);
            pairmin_(m4, q4, m5, q5);  pairmin_(m6, q6, m7, q7);
            pairmin_(m0, q0, m2, q2);  pairmin_(m4, q4, m6, q6);
            pairmin_(m0, q0, m4, q4);
            const float lmin = m0;                 // per-lane local min
            const unsigned lpay = q0;              // its payload

            // value-only wave min (bit-exact gmin), then ballot-select owner
            const float gmin = wave_min_f32_(lmin);
            const unsigned long long cand = __ballot(lmin == gmin);
            const int wl = (int)__builtin_ctzll(cand);
            const unsigned win = (unsigned)__builtin_amdgcn_readlane((int)lpay, wl);

            min_val = gmin;
            const unsigned jst = win >> 10;
            const unsigned rc1 = win & 0x3FFu;

            // issue next-row loads EARLY (clamped on sink); bookkeeping hides
            const int i_next = (int)rc1 - 1;                 // -1 if sink
            const int i_safe = (i_next < 0) ? 0 : i_next;
            crow = cb + (size_t)i_safe * n;
            cv0 = *(const float4*)(crow + 4 * lane);
            cv1 = *(const float4*)(crow + off2);
            a = gmin - u_lds[i_safe];             // LDS read in load shadow

            // pop bookkeeping: poison winner col on its owner lane
            const int owner = (int)((jst >> 2) & 63u);
            const int kwin  = (int)(((jst >> 8) << 2) | (jst & 3u));
            #pragma unroll
            for (int k = 0; k < 8; ++k) {
                if (k == kwin && lane == owner) {
                    shortfin_r[k] = short_r[k];
                    short_r[k] = INFINITY;
                    vwork_r[k] = -INFINITY;
                }
            }

            if (rc1 == 0u) { sink_j = (int)jst; break; }
            i = i_next;
        }

        if (sink_j >= 0) {
            // publish final labels/path (vectorized; lanes 61-63's 2nd quad
            // lands in the unread 500..511 pad -> literal offset, NOT off2)
            *(float4*)&shortest_lds[4 * lane] =
                make_float4(shortfin_r[0], shortfin_r[1], shortfin_r[2], shortfin_r[3]);
            *(int4*)&path_lds[4 * lane] =
                make_int4(path_r[0], path_r[1], path_r[2], path_r[3]);
            *(float4*)&shortest_lds[256 + 4 * lane] =
                make_float4(shortfin_r[4], shortfin_r[5], shortfin_r[6], shortfin_r[7]);
            *(int4*)&path_lds[256 + 4 * lane] =
                make_int4(path_r[4], path_r[5], path_r[6], path_r[7]);
            __syncthreads();

            // u-update for SR rows (col4row read BEFORE augmentation);
            // v-update for scanned cols (marker: vwork == -INF), register-local
            #pragma unroll
            for (int k = 0; k < 8; ++k) {
                const int t = lane + (k << 6);
                if (t < n && (sr_mask & (1u << k))) {
                    if (t == cur_row) u_lds[t] += min_val;
                    else              u_lds[t] += min_val - shortest_lds[col4row_lds[t]];
                }
            }
            #pragma unroll
            for (int k = 0; k < 8; ++k) {
                if (((init_mask >> k) & 1) && vwork_r[k] == -INFINITY)
                    v_r[k] -= min_val - shortfin_r[k];
            }
            __syncthreads();

            if (lane == 0) {   // augment alternating path
                int j = sink_j;
                for (;;) {
                    const int ii = path_lds[j];
                    row4col_lds[j] = ii;
                    const int tmp = col4row_lds[ii];
                    col4row_lds[ii] = j;
                    j = tmp;
                    if (ii == cur_row) break;
                }
            }
            __syncthreads();
        }

        // refresh payloads (b128 LDS reads) and reset per-row register state
        {
            const int4 r0 = *(const int4*)&row4col_lds[4 * lane];
            const int4 r1 = *(const int4*)&row4col_lds[off2];
            const int rr[8] = {r0.x, r0.y, r0.z, r0.w, r1.x, r1.y, r1.z, r1.w};
            #pragma unroll
            for (int k = 0; k < 8; ++k) {
                const int j = (k < 4) ? 4 * lane + k : 256 + 4 * lane + (k - 4);
                const bool valid = (init_mask >> k) & 1;
                pay_r[k] = valid ? (((unsigned)j << 10) | (unsigned)(rr[k] + 1))
                                 : 0xFFFFFFFFu;
                vwork_r[k] = valid ? v_r[k] : -INFINITY;
                short_r[k] = INFINITY;
                shortfin_r[k] = INFINITY;
                path_r[k] = -1;
            }
        }
        sr_mask = 0;
        __syncthreads();
    }

    for (int t = lane; t < n; t += 64)
        mapping[b * n + t] = col4row_lds[t];
}

// ---------------------------------------------------------------------------
// Phase 3: extrapolation (square problem => every row assigned; -1 guarded).
// ---------------------------------------------------------------------------
__global__ __launch_bounds__(256) void extrap_boxes_kernel(
    const float* __restrict__ p1_boxes, const float* __restrict__ p2_boxes,
    const float* __restrict__ toffs, const int* __restrict__ mapping,
    float* __restrict__ out_boxes)
{
    const int idx = blockIdx.x * blockDim.x + threadIdx.x;  // b*Mq + i
    if (idx >= Bq * Mq) return;
    const int b = idx / Mq;
    const float t0 = toffs[b * 3 + 0], t1 = toffs[b * 3 + 1], t2 = toffs[b * 3 + 2];
    const float factor = (t2 - t1) / (t1 - t0);
    const int m = mapping[idx];
    const float4 p2 = ((const float4*)p2_boxes)[idx];
    const float4 p1 = (m >= 0) ? ((const float4*)p1_boxes)[b * Nq + m] : p2;
    float4 o;
    o.x = p2.x + (p2.x - p1.x) * factor;
    o.y = p2.y + (p2.y - p1.y) * factor;
    o.z = fmaxf(p2.z + (p2.z - p1.z) * factor, 0.0f);
    o.w = fmaxf(p2.w + (p2.w - p1.w) * factor, 0.0f);
    ((float4*)out_boxes)[idx] = o;
}

__global__ __launch_bounds__(256) void extrap_logits_kernel(
    const float* __restrict__ p1_logits, const float* __restrict__ p2_logits,
    const int* __restrict__ mapping, float* __restrict__ out_logits)
{
    const int idx = blockIdx.x * blockDim.x + threadIdx.x;  // (b*Mq + i)*Cq + c
    if (idx >= Bq * Mq * Cq) return;
    const int c = idx % Cq;
    const int bi = idx / Cq;
    const int b = bi / Mq;
    const int m = mapping[bi];
    const float corr = (m >= 0) ? p1_logits[((size_t)b * Nq + m) * Cq + c] : 0.0f;
    out_logits[idx] = 0.5f * (p2_logits[idx] + corr);
}

// ---------------------------------------------------------------------------
extern "C" void kernel_launch(void* const* d_in, const int* in_sizes, int n_in,
                              void* d_out, int out_size, void* d_ws, size_t ws_size,
                              hipStream_t stream) {
    const float* p1_boxes  = (const float*)d_in[0];  // (B,N,4)
    const float* p1_logits = (const float*)d_in[1];  // (B,N,C)
    const float* p2_boxes  = (const float*)d_in[2];  // (B,M,4)
    const float* p2_logits = (const float*)d_in[3];  // (B,M,C)
    const float* toffs     = (const float*)d_in[4];  // (B,3)
    float* out = (float*)d_out;                      // boxes3 ++ logits3

    char* ws = (char*)d_ws;
    float* cost    = (float*)ws;                                   // 4 MB
    int*   mapping = (int*)  (ws + 4000000);                       // 8 KB
    float* v0      = (float*)(ws + 4008000);                       // 8 KB
    int*   amin    = (int*)  (ws + 4016000);                       // 8 KB

    dim3 cgrid((Nq + 15) / 16, (Mq + 15) / 16, Bq);
    cost_kernel<<<cgrid, 256, 0, stream>>>(p1_boxes, p1_logits, p2_boxes, p2_logits, cost);

    colred_kernel<<<dim3(2, Bq), 256, 0, stream>>>(cost, v0, amin);

    lsa_kernel<<<Bq, 64, 0, stream>>>(cost, v0, amin, mapping);

    extrap_boxes_kernel<<<(Bq * Mq + 255) / 256, 256, 0, stream>>>(
        p1_boxes, p2_boxes, toffs, mapping, out);
    extrap_logits_kernel<<<(Bq * Mq * Cq + 255) / 256, 256, 0, stream>>>(
        p1_logits, p2_logits, mapping, out + Bq * Mq * 4);
}